// Round 7
// baseline (108.632 us; speedup 1.0000x reference)
//
#include <hip/hip_runtime.h>

// CoAttention, 3-kernel pipeline. R18 = R17 (106.85us) + k_mid T14
// register-prefetch (ONLY change):
//  k_mid: both paths issue chunk-1 global loads into REGISTERS right after
//         chunk-0 staging, overlap them with chunk-0 compute, write to LDS
//         after the barrier. No LDS growth (38400B, 3 blocks/CU unchanged),
//         +32..64 VGPR transient. Barriers 4 -> 3 per path.
// R17 lesson: in-block staging/compute overlap is the dominant lever here
// (k_final dbuf: predicted -1, got -6.5); cross-block TLP at 2-3 blocks/CU
// does NOT hide staging latency.
// Carried: native (__bf16) cvt; EN/ET bf16; k_final LDS double-buffer.
// Budget model: ~88us fixed (harness poison fills @ 76-80% HBM peak) +
// ~19us controllable (projE ~2.5, mid ~10, final ~3.5, gaps ~3).

#define NEGC (-1e12f)
#define TWO_LOG2E 2.8853900817779268f
#define LOG2E 1.4426950408889634f
#define N2LOG2E (-2.8853900817779268f)

typedef __attribute__((ext_vector_type(8))) short bf16x8;
typedef __attribute__((ext_vector_type(4))) float f32x4;

__device__ __forceinline__ short f2bf(float x)   // RNE f32->bf16 (native cvt)
{
    return __builtin_bit_cast(short, (__bf16)x);
}

// --------------------------------------------------------------- k_projE
// E1 = exp(2*(ctx1 @ Wh[:256] + bh)), E2 = exp(2*(ctx2 @ Wh[256:])).
// 32x64 tile, single K=256 chunk. grid (32,4,2).
__global__ __launch_bounds__(256) void k_projE(
    const float* __restrict__ ctx1, const float* __restrict__ ctx2,
    const float* __restrict__ Wh, const float* __restrict__ bh,
    const float* __restrict__ mask1, const float* __restrict__ mask2,
    float* __restrict__ E1, float* __restrict__ E2,
    float* __restrict__ p1, float* __restrict__ p2,
    float* __restrict__ S1, float* __restrict__ S2)
{
    const int t  = threadIdx.x;
    const int g  = blockIdx.z;
    const int r0 = blockIdx.x * 32;       // rows = l*2+b in [0,1024)
    const int n0 = blockIdx.y * 64;       // N in [0,256)

    const float* A    = g ? ctx2       : ctx1;
    const float* W    = g ? Wh + 65536 : Wh;
    const float* bias = g ? 0          : bh;
    float*       outp = g ? E2         : E1;

    if (g == 0 && blockIdx.x == 0 && blockIdx.y == 0) {
        for (int idx = t; idx < 1024; idx += 256) {
            int row = idx >> 1, b = idx & 1;
            p1[b * 512 + row] = __builtin_amdgcn_exp2f(LOG2E * (1.f - mask1[idx]) * NEGC);
            p2[b * 512 + row] = __builtin_amdgcn_exp2f(LOG2E * (1.f - mask2[idx]) * NEGC);
            S1[b * 512 + row] = 0.f;
            S2[b * 512 + row] = 0.f;
        }
    }

    __shared__ __align__(16) short Abf[32 * 264];   // [m][k] bf16, full K
    __shared__ __align__(16) short Bbf[64 * 264];   // [n][k] bf16 (W^T), full K

    #pragma unroll
    for (int i = 0; i < 8; ++i) {                   // A: 32 rows x 256 k
        int slot = i * 256 + t;
        int r = slot >> 6, kq = (slot & 63) << 2;
        float4 v = *(const float4*)(A + (r0 + r) * 256 + kq);
        short4 s; s.x = f2bf(v.x); s.y = f2bf(v.y); s.z = f2bf(v.z); s.w = f2bf(v.w);
        *(short4*)(Abf + r * 264 + kq) = s;
    }
    #pragma unroll
    for (int i = 0; i < 16; ++i) {                  // B: 256 k x 64 n -> B^T
        int slot = i * 256 + t;
        int bk = slot >> 4, bn4 = (slot & 15) << 2;
        float4 v = *(const float4*)(W + bk * 256 + n0 + bn4);
        Bbf[(bn4 + 0) * 264 + bk] = f2bf(v.x);
        Bbf[(bn4 + 1) * 264 + bk] = f2bf(v.y);
        Bbf[(bn4 + 2) * 264 + bk] = f2bf(v.z);
        Bbf[(bn4 + 3) * 264 + bk] = f2bf(v.w);
    }
    __syncthreads();

    const int w    = t >> 6;
    const int lane = t & 63;
    const int quad = lane >> 4;
    const int lr   = lane & 15;
    const int h    = w & 1;               // row-half: rows r0 + h*16 + ...
    const int c    = w >> 1;              // col-half: cols n0 + c*32 + nc*16

    f32x4 acc[2] = {};

    #pragma unroll
    for (int s = 0; s < 8; ++s) {
        const int kb = s * 32 + quad * 8;
        bf16x8 a = *(const bf16x8*)(Abf + (h * 16 + lr) * 264 + kb);
        #pragma unroll
        for (int nc = 0; nc < 2; ++nc) {
            bf16x8 b = *(const bf16x8*)(Bbf + (c * 32 + nc * 16 + lr) * 264 + kb);
            acc[nc] = __builtin_amdgcn_mfma_f32_16x16x32_bf16(a, b, acc[nc], 0, 0, 0);
        }
    }

    #pragma unroll
    for (int nc = 0; nc < 2; ++nc) {
        const int col = n0 + c * 32 + nc * 16 + lr;
        const float bv = bias ? bias[col] : 0.f;
        #pragma unroll
        for (int reg = 0; reg < 4; ++reg) {
            int row  = r0 + h * 16 + quad * 4 + reg;   // = l*2+b
            int orow = ((row & 1) << 9) + (row >> 1);
            float v = acc[nc][reg] + bv;
            outp[orow * 256 + col] = __builtin_amdgcn_exp2f(v * TWO_LOG2E);
        }
    }
}

// ---------------------------------------------------------------- k_mid
// PAIR: acc += w.x/x0 + w.y/x1 + w.z/x2 + w.w/x3 with 2 rcp via pairing.
#define PAIR(AV, QV, WV, ACC) do {                                    \
    float x0_ = fmaf(AV.x, QV.x, 1.f);                                \
    float x1_ = fmaf(AV.y, QV.y, 1.f);                                \
    float x2_ = fmaf(AV.z, QV.z, 1.f);                                \
    float x3_ = fmaf(AV.w, QV.w, 1.f);                                \
    float r01_ = __builtin_amdgcn_rcpf(x0_ * x1_);                    \
    float r23_ = __builtin_amdgcn_rcpf(x2_ * x3_);                    \
    float z01_ = fmaf(WV.y, x0_, WV.x * x1_);                         \
    float z23_ = fmaf(WV.w, x2_, WV.z * x3_);                         \
    ACC = fmaf(r01_, z01_, ACC);                                      \
    ACC = fmaf(r23_, z23_, ACC);                                      \
} while (0)

__global__ __launch_bounds__(256) void k_mid(
    const float* __restrict__ ctx1, const float* __restrict__ ctx2,
    const float* __restrict__ W12, const float* __restrict__ b12,
    const float* __restrict__ W21, const float* __restrict__ b21,
    const float* __restrict__ E1g, const float* __restrict__ E2g,
    const float* __restrict__ wo,
    const float* __restrict__ p1g, const float* __restrict__ p2g,
    float* __restrict__ P12, float* __restrict__ U1,
    float* __restrict__ P21, float* __restrict__ U2,
    short* __restrict__ EN, short* __restrict__ ET,
    float* __restrict__ S1, float* __restrict__ S2)
{
    // LDS union: aff path needs 38400 B (2x 32*132 f32 + 32*36 f32);
    // gemm path needs 34816 B (2x 64*136 bf16).
    __shared__ __align__(16) char smem[38400];

    const int t   = threadIdx.x;
    const int bid = blockIdx.x;
    const int r3  = bid % 3;

    if (r3 == 2) {
        // ---------------- GEMM path: 4 U/P projections (k_final inputs only)
        const int idx = bid / 3;              // [0,256)
        const int g   = idx >> 6;             // 64 blocks per projection
        const int r0  = (idx & 15) * 64;
        const int n0  = ((idx >> 4) & 3) * 64;

        const float* A; const float* W; const float* bias; float* outp;
        switch (g) {
          case 0:  A = ctx2; W = W12;         bias = b12; outp = P12; break;
          case 1:  A = ctx1; W = W12 + 65536; bias = 0;   outp = U1;  break;
          case 2:  A = ctx1; W = W21;         bias = b21; outp = P21; break;
          default: A = ctx2; W = W21 + 65536; bias = 0;   outp = U2;  break;
        }

        short* Abf = (short*)smem;            // [64][136]
        short* Bbf = Abf + 64 * 136;          // [64][136]

        const int w    = t >> 6;
        const int lane = t & 63;
        const int quad = lane >> 4;
        const int lr   = lane & 15;

        f32x4 acc[4] = {};

        // ---- chunk 0: direct stage
        #pragma unroll
        for (int i = 0; i < 8; ++i) {             // A: 64 rows x 128 k
            int slot = i * 256 + t;
            int r = slot >> 5, kq = (slot & 31) << 2;
            float4 v = *(const float4*)(A + (r0 + r) * 256 + kq);
            short4 s; s.x = f2bf(v.x); s.y = f2bf(v.y); s.z = f2bf(v.z); s.w = f2bf(v.w);
            *(short4*)(Abf + r * 136 + kq) = s;
        }
        #pragma unroll
        for (int i = 0; i < 8; ++i) {             // B: 128 k x 64 n -> B^T
            int slot = i * 256 + t;
            int bk = slot >> 4, bn4 = (slot & 15) << 2;
            float4 v = *(const float4*)(W + bk * 256 + n0 + bn4);
            Bbf[(bn4 + 0) * 136 + bk] = f2bf(v.x);
            Bbf[(bn4 + 1) * 136 + bk] = f2bf(v.y);
            Bbf[(bn4 + 2) * 136 + bk] = f2bf(v.z);
            Bbf[(bn4 + 3) * 136 + bk] = f2bf(v.w);
        }
        // ---- chunk 1: prefetch to regs (in flight during compute 0)
        float4 pa[8], pb[8];
        #pragma unroll
        for (int i = 0; i < 8; ++i) {
            int slot = i * 256 + t;
            int r = slot >> 5, kq = (slot & 31) << 2;
            pa[i] = *(const float4*)(A + (r0 + r) * 256 + 128 + kq);
        }
        #pragma unroll
        for (int i = 0; i < 8; ++i) {
            int slot = i * 256 + t;
            int bk = slot >> 4, bn4 = (slot & 15) << 2;
            pb[i] = *(const float4*)(W + (128 + bk) * 256 + n0 + bn4);
        }
        __syncthreads();
        #pragma unroll
        for (int s = 0; s < 4; ++s) {             // compute chunk 0
            const int kb = s * 32 + quad * 8;
            bf16x8 a = *(const bf16x8*)(Abf + (w * 16 + lr) * 136 + kb);
            #pragma unroll
            for (int nc = 0; nc < 4; ++nc) {
                bf16x8 b = *(const bf16x8*)(Bbf + (nc * 16 + lr) * 136 + kb);
                acc[nc] = __builtin_amdgcn_mfma_f32_16x16x32_bf16(a, b, acc[nc], 0, 0, 0);
            }
        }
        __syncthreads();
        #pragma unroll
        for (int i = 0; i < 8; ++i) {             // write prefetched A
            int slot = i * 256 + t;
            int r = slot >> 5, kq = (slot & 31) << 2;
            short4 s; s.x = f2bf(pa[i].x); s.y = f2bf(pa[i].y);
            s.z = f2bf(pa[i].z); s.w = f2bf(pa[i].w);
            *(short4*)(Abf + r * 136 + kq) = s;
        }
        #pragma unroll
        for (int i = 0; i < 8; ++i) {             // write prefetched B
            int slot = i * 256 + t;
            int bk = slot >> 4, bn4 = (slot & 15) << 2;
            Bbf[(bn4 + 0) * 136 + bk] = f2bf(pb[i].x);
            Bbf[(bn4 + 1) * 136 + bk] = f2bf(pb[i].y);
            Bbf[(bn4 + 2) * 136 + bk] = f2bf(pb[i].z);
            Bbf[(bn4 + 3) * 136 + bk] = f2bf(pb[i].w);
        }
        __syncthreads();
        #pragma unroll
        for (int s = 0; s < 4; ++s) {             // compute chunk 1
            const int kb = s * 32 + quad * 8;
            bf16x8 a = *(const bf16x8*)(Abf + (w * 16 + lr) * 136 + kb);
            #pragma unroll
            for (int nc = 0; nc < 4; ++nc) {
                bf16x8 b = *(const bf16x8*)(Bbf + (nc * 16 + lr) * 136 + kb);
                acc[nc] = __builtin_amdgcn_mfma_f32_16x16x32_bf16(a, b, acc[nc], 0, 0, 0);
            }
        }

        #pragma unroll
        for (int nc = 0; nc < 4; ++nc) {
            const int col = n0 + nc * 16 + lr;
            const float bv = bias ? bias[col] : 0.f;
            #pragma unroll
            for (int reg = 0; reg < 4; ++reg) {
                int row  = r0 + w * 16 + quad * 4 + reg;   // = l*2+b
                int orow = ((row & 1) << 9) + (row >> 1);
                outp[orow * 256 + col] = acc[nc][reg] + bv;
            }
        }
    } else {
        // ---------------- affinity path (math identical to R16)
        const int aidx = (bid / 3) * 2 + r3;  // [0,512)
        const int l0 = (aidx & 15) * 32;
        const int m0 = ((aidx >> 4) & 15) * 32;
        const int b  = aidx >> 8;

        float* E1s  = (float*)smem;           // [32][132]
        float* E2s  = E1s + 32 * 132;         // [32][132]
        float* affs = E2s + 32 * 132;         // [32][36]

        const int tl = t >> 4, tm = t & 15;   // cells: l in {tl,tl+16}, m in {tm,tm+16}
        float acc[2][2] = {};

        // ---- chunk 0: direct stage
        #pragma unroll
        for (int i = 0; i < 4; ++i) {
            int slot = i * 256 + t;
            int r = slot >> 5, kq = (slot & 31) << 2;
            *(float4*)(E1s + r * 132 + kq) =
                *(const float4*)(E1g + (((b << 9) + l0 + r) << 8) + kq);
            *(float4*)(E2s + r * 132 + kq) =
                *(const float4*)(E2g + (((b << 9) + m0 + r) << 8) + kq);
        }
        // ---- chunk 1: prefetch to regs
        float4 pe1[4], pe2[4];
        #pragma unroll
        for (int i = 0; i < 4; ++i) {
            int slot = i * 256 + t;
            int r = slot >> 5, kq = (slot & 31) << 2;
            pe1[i] = *(const float4*)(E1g + (((b << 9) + l0 + r) << 8) + 128 + kq);
            pe2[i] = *(const float4*)(E2g + (((b << 9) + m0 + r) << 8) + 128 + kq);
        }
        __syncthreads();

#define AFFCHUNK(KC) do {                                                 \
    _Pragma("unroll 4")                                                   \
    for (int k0 = 0; k0 < 128; k0 += 4) {                                 \
        const float4 w  = *(const float4*)(wo + (KC) + k0);               \
        const float4 a0 = *(const float4*)(E1s + tl * 132 + k0);          \
        const float4 a1 = *(const float4*)(E1s + (tl + 16) * 132 + k0);   \
        const float4 q0 = *(const float4*)(E2s + tm * 132 + k0);          \
        const float4 q1 = *(const float4*)(E2s + (tm + 16) * 132 + k0);   \
        PAIR(a0, q0, w, acc[0][0]);                                       \
        PAIR(a0, q1, w, acc[0][1]);                                       \
        PAIR(a1, q0, w, acc[1][0]);                                       \
        PAIR(a1, q1, w, acc[1][1]);                                       \
    }                                                                     \
} while (0)

        AFFCHUNK(0);
        __syncthreads();
        #pragma unroll
        for (int i = 0; i < 4; ++i) {             // write prefetched chunk 1
            int slot = i * 256 + t;
            int r = slot >> 5, kq = (slot & 31) << 2;
            *(float4*)(E1s + r * 132 + kq) = pe1[i];
            *(float4*)(E2s + r * 132 + kq) = pe2[i];
        }
        __syncthreads();
        AFFCHUNK(128);
#undef AFFCHUNK
        __syncthreads();

        // aff = -2*acc (the -2*wo factor folded); E = exp(aff), SW cancels
        affs[tl * 36 + tm]             = __builtin_amdgcn_exp2f(acc[0][0] * N2LOG2E);
        affs[tl * 36 + tm + 16]        = __builtin_amdgcn_exp2f(acc[0][1] * N2LOG2E);
        affs[(tl + 16) * 36 + tm]      = __builtin_amdgcn_exp2f(acc[1][0] * N2LOG2E);
        affs[(tl + 16) * 36 + tm + 16] = __builtin_amdgcn_exp2f(acc[1][1] * N2LOG2E);
        __syncthreads();

        const int r  = t >> 3;
        const int c4 = (t & 7) << 2;
        // natural: EN[l][m]=bf16(E*p1[l]); S1[l]+=sum_m E*p2[m]
        {
            float4 e = *(const float4*)(affs + r * 36 + c4);
            const float p1r = p1g[(b << 9) + l0 + r];
            short4 vn;
            vn.x = f2bf(e.x * p1r); vn.y = f2bf(e.y * p1r);
            vn.z = f2bf(e.z * p1r); vn.w = f2bf(e.w * p1r);
            *(short4*)(EN + (((b << 9) + l0 + r) << 9) + m0 + c4) = vn;
            float4 p2v = *(const float4*)(p2g + (b << 9) + m0 + c4);
            float s = (e.x * p2v.x + e.y * p2v.y) + (e.z * p2v.z + e.w * p2v.w);
            s += __shfl_xor(s, 1, 64);
            s += __shfl_xor(s, 2, 64);
            s += __shfl_xor(s, 4, 64);
            if ((t & 7) == 0) atomicAdd(S1 + (b << 9) + l0 + r, s);
        }
        // transposed: ET[m][l]=bf16(E^T*p2[m]); S2[m]+=sum_l E*p1[l]
        {
            float4 te;
            te.x = affs[(c4 + 0) * 36 + r];
            te.y = affs[(c4 + 1) * 36 + r];
            te.z = affs[(c4 + 2) * 36 + r];
            te.w = affs[(c4 + 3) * 36 + r];
            const float p2r = p2g[(b << 9) + m0 + r];
            short4 vt;
            vt.x = f2bf(te.x * p2r); vt.y = f2bf(te.y * p2r);
            vt.z = f2bf(te.z * p2r); vt.w = f2bf(te.w * p2r);
            *(short4*)(ET + (((b << 9) + m0 + r) << 9) + l0 + c4) = vt;
            float4 p1v = *(const float4*)(p1g + (b << 9) + l0 + c4);
            float s = (te.x * p1v.x + te.y * p1v.y) + (te.z * p1v.z + te.w * p1v.w);
            s += __shfl_xor(s, 1, 64);
            s += __shfl_xor(s, 2, 64);
            s += __shfl_xor(s, 4, 64);
            if ((t & 7) == 0) atomicAdd(S2 + (b << 9) + m0 + r, s);
        }
    }
}

// --------------------------------------------------------------- k_final
// Double-buffered LDS: stage chunk c+1 overlaps MFMA on chunk c.
__global__ __launch_bounds__(256) void k_final(
    const short* __restrict__ EN, const short* __restrict__ ET,
    const float* __restrict__ U1, const float* __restrict__ U2,
    const float* __restrict__ P12, const float* __restrict__ P21,
    const float* __restrict__ S1, const float* __restrict__ S2,
    float* __restrict__ out)
{
    const int t   = threadIdx.x;
    const int r0  = blockIdx.x * 32, n0 = blockIdx.y * 32;
    const int dir = blockIdx.z >> 1, b = blockIdx.z & 1;
    const short* Ag = (dir == 0 ? ET  : EN)  + b * 262144;  // [row][k] bf16, stride 512
    const float* Sg = (dir == 0 ? S1  : S2)  + b * 512;
    const float* Bg = (dir == 0 ? U1  : U2)  + b * 131072;  // [k][n], stride 256
    const float* Pg = (dir == 0 ? P12 : P21) + b * 131072;  // [row][n], stride 256
    float* o = out + (dir == 0 ? 262144 : 0);

    __shared__ __align__(16) short Abf0[32 * 136];  // ping
    __shared__ __align__(16) short Bbf0[32 * 136];
    __shared__ __align__(16) short Abf1[32 * 136];  // pong
    __shared__ __align__(16) short Bbf1[32 * 136];
    __shared__ __align__(16) float rs[512];

    for (int i = t; i < 512; i += 256)
        rs[i] = __builtin_amdgcn_rcpf(Sg[i]);

    const int w    = t >> 6;
    const int lane = t & 63;
    const int quad = lane >> 4;
    const int lr   = lane & 15;
    const int wr   = (w >> 1) << 4, wc = (w & 1) << 4;
    const int col  = n0 + wc + lr;

    float pre[4];                          // Pg epilogue prefetch
    #pragma unroll
    for (int reg = 0; reg < 4; ++reg) {
        const int m = r0 + wr + quad * 4 + reg;
        pre[reg] = Pg[(m << 8) + col];
    }
    __syncthreads();                       // rs visible

    f32x4 acc = {};

#define STAGE(Ab, Bb, kc) do {                                            \
    _Pragma("unroll")                                                     \
    for (int i = 0; i < 2; ++i) {              /* A: raw bf16 copy */     \
        int slot = i * 256 + t;                                           \
        int r = slot >> 4, k8 = (slot & 15) << 3;                         \
        *(bf16x8*)((Ab) + r * 136 + k8) =                                 \
            *(const bf16x8*)(Ag + ((r0 + r) << 9) + (kc) + k8);           \
    }                                                                     \
    _Pragma("unroll")                                                     \
    for (int i = 0; i < 4; ++i) {              /* B: rs folded */         \
        int slot = i * 256 + t;                                           \
        int bk = slot >> 3, bn4 = (slot & 7) << 2;                        \
        float4 v = *(const float4*)(Bg + (((kc) + bk) << 8) + n0 + bn4);  \
        const float rsv = rs[(kc) + bk];                                  \
        (Bb)[(bn4 + 0) * 136 + bk] = f2bf(v.x * rsv);                     \
        (Bb)[(bn4 + 1) * 136 + bk] = f2bf(v.y * rsv);                     \
        (Bb)[(bn4 + 2) * 136 + bk] = f2bf(v.z * rsv);                     \
        (Bb)[(bn4 + 3) * 136 + bk] = f2bf(v.w * rsv);                     \
    }                                                                     \
} while (0)

#define COMPUTE(Ab, Bb) do {                                              \
    _Pragma("unroll")                                                     \
    for (int s = 0; s < 4; ++s) {                                         \
        const int kb = s * 32 + quad * 8;                                 \
        bf16x8 a_  = *(const bf16x8*)((Ab) + (wr + lr) * 136 + kb);       \
        bf16x8 bb_ = *(const bf16x8*)((Bb) + (wc + lr) * 136 + kb);       \
        acc = __builtin_amdgcn_mfma_f32_16x16x32_bf16(a_, bb_, acc, 0, 0, 0); \
    }                                                                     \
} while (0)

    STAGE(Abf0, Bbf0, 0);
    __syncthreads();                       // buf0 ready
    STAGE(Abf1, Bbf1, 128);                // overlap with compute(0)
    COMPUTE(Abf0, Bbf0);
    __syncthreads();                       // buf1 ready, buf0 reads done
    STAGE(Abf0, Bbf0, 256);
    COMPUTE(Abf1, Bbf1);
    __syncthreads();
    STAGE(Abf1, Bbf1, 384);
    COMPUTE(Abf0, Bbf0);
    __syncthreads();
    COMPUTE(Abf1, Bbf1);

#undef STAGE
#undef COMPUTE

    #pragma unroll
    for (int reg = 0; reg < 4; ++reg) {
        const int m = r0 + wr + quad * 4 + reg;
        float v = acc[reg] + pre[reg];
        float tv = 1.f - 2.f * __builtin_amdgcn_rcpf(
                       __builtin_amdgcn_exp2f(v * TWO_LOG2E) + 1.f);
        o[((m << 1) + b) * 256 + col] = tv;
    }
}

// ---------------------------------------------------------------- launch
extern "C" void kernel_launch(void* const* d_in, const int* in_sizes, int n_in,
                              void* d_out, int out_size, void* d_ws, size_t ws_size,
                              hipStream_t stream)
{
    const float* ctx1 = (const float*)d_in[0];
    const float* ctx2 = (const float*)d_in[1];
    const float* m1   = (const float*)d_in[2];
    const float* m2   = (const float*)d_in[3];
    const float* Wh   = (const float*)d_in[4];
    const float* bh   = (const float*)d_in[5];
    const float* wo   = (const float*)d_in[6];
    const float* W12  = (const float*)d_in[7];
    const float* b12  = (const float*)d_in[8];
    const float* W21  = (const float*)d_in[9];
    const float* b21  = (const float*)d_in[10];
    float* out = (float*)d_out;
    float* ws  = (float*)d_ws;

    float* E1  = ws;                 // 262144
    float* E2  = E1  + 262144;
    float* P12 = E2  + 262144;
    float* U1  = P12 + 262144;
    float* P21 = U1  + 262144;
    float* U2  = P21 + 262144;
    float* p1  = U2  + 262144;       // 1024
    float* p2  = p1  + 1024;
    float* S1  = p2  + 1024;         // 1024
    float* S2  = S1  + 1024;
    float* ENf = S2  + 1024;         // 524288 floats reserved
    float* ETf = ENf + 524288;       // 524288 floats reserved
    short* EN16 = (short*)ENf;       // [2][512][512] bf16
    short* ET16 = (short*)ETf;       // [2][512][512] bf16

    hipLaunchKernelGGL(k_projE, dim3(32, 4, 2), dim3(256), 0, stream,
                       ctx1, ctx2, Wh, bh, m1, m2, E1, E2, p1, p2, S1, S2);
    hipLaunchKernelGGL(k_mid, dim3(768, 1, 1), dim3(256), 0, stream,
                       ctx1, ctx2, W12, b12, W21, b21,
                       E1, E2, wo, p1, p2,
                       P12, U1, P21, U2, EN16, ET16, S1, S2);
    hipLaunchKernelGGL(k_final, dim3(16, 8, 4), dim3(256), 0, stream,
                       EN16, ET16, U1, U2, P12, P21, S1, S2, out);
}

// Round 8
// 107.025 us; speedup vs baseline: 1.0150x; 1.0150x over previous
//
#include <hip/hip_runtime.h>

// CoAttention, 3-kernel pipeline. R19 = R17 (best, 106.85us) + k_mid
// XCD-chunked bid swizzle (ONLY change):
//  k_mid: lbid = (bid&7)*96 + (bid>>3)  (bijective, 768=8*96). HW round-
//         robins raw bid%8 across the 8 XCDs; relabeling gives each XCD 96
//         CONSECUTIVE logical blocks, which share E1/E2/W/ctx panels ->
//         panel refetches become per-XCD L2 hits (cold FETCH was 18MB vs
//         ~6MB ideal).
// R18 lesson (reverted): k_mid reg-prefetch = +1.8us (extra barrier+serial
// LDS write; 3 blocks/CU already hides chunk-1 latency there).
// R17 lesson: in-block staging/compute overlap is the dominant lever for
// 2-blocks/CU kernels (k_final dbuf -6.5us).
// Carried: native (__bf16) cvt; EN/ET bf16; k_final LDS double-buffer.
// Budget model: ~88us fixed (harness poison fills @ 76-80% HBM peak) +
// ~19us controllable (projE ~2.5, mid ~10, final ~3.5, gaps ~3).

#define NEGC (-1e12f)
#define TWO_LOG2E 2.8853900817779268f
#define LOG2E 1.4426950408889634f
#define N2LOG2E (-2.8853900817779268f)

typedef __attribute__((ext_vector_type(8))) short bf16x8;
typedef __attribute__((ext_vector_type(4))) float f32x4;

__device__ __forceinline__ short f2bf(float x)   // RNE f32->bf16 (native cvt)
{
    return __builtin_bit_cast(short, (__bf16)x);
}

// --------------------------------------------------------------- k_projE
// E1 = exp(2*(ctx1 @ Wh[:256] + bh)), E2 = exp(2*(ctx2 @ Wh[256:])).
// 32x64 tile, single K=256 chunk. grid (32,4,2).
__global__ __launch_bounds__(256) void k_projE(
    const float* __restrict__ ctx1, const float* __restrict__ ctx2,
    const float* __restrict__ Wh, const float* __restrict__ bh,
    const float* __restrict__ mask1, const float* __restrict__ mask2,
    float* __restrict__ E1, float* __restrict__ E2,
    float* __restrict__ p1, float* __restrict__ p2,
    float* __restrict__ S1, float* __restrict__ S2)
{
    const int t  = threadIdx.x;
    const int g  = blockIdx.z;
    const int r0 = blockIdx.x * 32;       // rows = l*2+b in [0,1024)
    const int n0 = blockIdx.y * 64;       // N in [0,256)

    const float* A    = g ? ctx2       : ctx1;
    const float* W    = g ? Wh + 65536 : Wh;
    const float* bias = g ? 0          : bh;
    float*       outp = g ? E2         : E1;

    if (g == 0 && blockIdx.x == 0 && blockIdx.y == 0) {
        for (int idx = t; idx < 1024; idx += 256) {
            int row = idx >> 1, b = idx & 1;
            p1[b * 512 + row] = __builtin_amdgcn_exp2f(LOG2E * (1.f - mask1[idx]) * NEGC);
            p2[b * 512 + row] = __builtin_amdgcn_exp2f(LOG2E * (1.f - mask2[idx]) * NEGC);
            S1[b * 512 + row] = 0.f;
            S2[b * 512 + row] = 0.f;
        }
    }

    __shared__ __align__(16) short Abf[32 * 264];   // [m][k] bf16, full K
    __shared__ __align__(16) short Bbf[64 * 264];   // [n][k] bf16 (W^T), full K

    #pragma unroll
    for (int i = 0; i < 8; ++i) {                   // A: 32 rows x 256 k
        int slot = i * 256 + t;
        int r = slot >> 6, kq = (slot & 63) << 2;
        float4 v = *(const float4*)(A + (r0 + r) * 256 + kq);
        short4 s; s.x = f2bf(v.x); s.y = f2bf(v.y); s.z = f2bf(v.z); s.w = f2bf(v.w);
        *(short4*)(Abf + r * 264 + kq) = s;
    }
    #pragma unroll
    for (int i = 0; i < 16; ++i) {                  // B: 256 k x 64 n -> B^T
        int slot = i * 256 + t;
        int bk = slot >> 4, bn4 = (slot & 15) << 2;
        float4 v = *(const float4*)(W + bk * 256 + n0 + bn4);
        Bbf[(bn4 + 0) * 264 + bk] = f2bf(v.x);
        Bbf[(bn4 + 1) * 264 + bk] = f2bf(v.y);
        Bbf[(bn4 + 2) * 264 + bk] = f2bf(v.z);
        Bbf[(bn4 + 3) * 264 + bk] = f2bf(v.w);
    }
    __syncthreads();

    const int w    = t >> 6;
    const int lane = t & 63;
    const int quad = lane >> 4;
    const int lr   = lane & 15;
    const int h    = w & 1;               // row-half: rows r0 + h*16 + ...
    const int c    = w >> 1;              // col-half: cols n0 + c*32 + nc*16

    f32x4 acc[2] = {};

    #pragma unroll
    for (int s = 0; s < 8; ++s) {
        const int kb = s * 32 + quad * 8;
        bf16x8 a = *(const bf16x8*)(Abf + (h * 16 + lr) * 264 + kb);
        #pragma unroll
        for (int nc = 0; nc < 2; ++nc) {
            bf16x8 b = *(const bf16x8*)(Bbf + (c * 32 + nc * 16 + lr) * 264 + kb);
            acc[nc] = __builtin_amdgcn_mfma_f32_16x16x32_bf16(a, b, acc[nc], 0, 0, 0);
        }
    }

    #pragma unroll
    for (int nc = 0; nc < 2; ++nc) {
        const int col = n0 + c * 32 + nc * 16 + lr;
        const float bv = bias ? bias[col] : 0.f;
        #pragma unroll
        for (int reg = 0; reg < 4; ++reg) {
            int row  = r0 + h * 16 + quad * 4 + reg;   // = l*2+b
            int orow = ((row & 1) << 9) + (row >> 1);
            float v = acc[nc][reg] + bv;
            outp[orow * 256 + col] = __builtin_amdgcn_exp2f(v * TWO_LOG2E);
        }
    }
}

// ---------------------------------------------------------------- k_mid
// PAIR: acc += w.x/x0 + w.y/x1 + w.z/x2 + w.w/x3 with 2 rcp via pairing.
#define PAIR(AV, QV, WV, ACC) do {                                    \
    float x0_ = fmaf(AV.x, QV.x, 1.f);                                \
    float x1_ = fmaf(AV.y, QV.y, 1.f);                                \
    float x2_ = fmaf(AV.z, QV.z, 1.f);                                \
    float x3_ = fmaf(AV.w, QV.w, 1.f);                                \
    float r01_ = __builtin_amdgcn_rcpf(x0_ * x1_);                    \
    float r23_ = __builtin_amdgcn_rcpf(x2_ * x3_);                    \
    float z01_ = fmaf(WV.y, x0_, WV.x * x1_);                         \
    float z23_ = fmaf(WV.w, x2_, WV.z * x3_);                         \
    ACC = fmaf(r01_, z01_, ACC);                                      \
    ACC = fmaf(r23_, z23_, ACC);                                      \
} while (0)

__global__ __launch_bounds__(256) void k_mid(
    const float* __restrict__ ctx1, const float* __restrict__ ctx2,
    const float* __restrict__ W12, const float* __restrict__ b12,
    const float* __restrict__ W21, const float* __restrict__ b21,
    const float* __restrict__ E1g, const float* __restrict__ E2g,
    const float* __restrict__ wo,
    const float* __restrict__ p1g, const float* __restrict__ p2g,
    float* __restrict__ P12, float* __restrict__ U1,
    float* __restrict__ P21, float* __restrict__ U2,
    short* __restrict__ EN, short* __restrict__ ET,
    float* __restrict__ S1, float* __restrict__ S2)
{
    // LDS union: aff path needs 38400 B (2x 32*132 f32 + 32*36 f32);
    // gemm path needs 34816 B (2x 64*136 bf16).
    __shared__ __align__(16) char smem[38400];

    const int t   = threadIdx.x;
    // XCD-chunked bijective swizzle: HW assigns raw bid round-robin to XCDs
    // (xcd = bid%8). Relabel so each XCD gets 96 consecutive logical blocks,
    // which share E1/E2/W/ctx panels -> per-XCD L2 reuse.
    const int bid = (blockIdx.x & 7) * 96 + (blockIdx.x >> 3);
    const int r3  = bid % 3;

    if (r3 == 2) {
        // ---------------- GEMM path: 4 U/P projections (k_final inputs only)
        const int idx = bid / 3;              // [0,256)
        const int g   = idx >> 6;             // 64 blocks per projection
        const int r0  = (idx & 15) * 64;
        const int n0  = ((idx >> 4) & 3) * 64;

        const float* A; const float* W; const float* bias; float* outp;
        switch (g) {
          case 0:  A = ctx2; W = W12;         bias = b12; outp = P12; break;
          case 1:  A = ctx1; W = W12 + 65536; bias = 0;   outp = U1;  break;
          case 2:  A = ctx1; W = W21;         bias = b21; outp = P21; break;
          default: A = ctx2; W = W21 + 65536; bias = 0;   outp = U2;  break;
        }

        short* Abf = (short*)smem;            // [64][136]
        short* Bbf = Abf + 64 * 136;          // [64][136]

        const int w    = t >> 6;
        const int lane = t & 63;
        const int quad = lane >> 4;
        const int lr   = lane & 15;

        f32x4 acc[4] = {};

        for (int kc = 0; kc < 256; kc += 128) {
            #pragma unroll
            for (int i = 0; i < 8; ++i) {             // A: 64 rows x 128 k
                int slot = i * 256 + t;
                int r = slot >> 5, kq = (slot & 31) << 2;
                float4 v = *(const float4*)(A + (r0 + r) * 256 + kc + kq);
                short4 s; s.x = f2bf(v.x); s.y = f2bf(v.y); s.z = f2bf(v.z); s.w = f2bf(v.w);
                *(short4*)(Abf + r * 136 + kq) = s;
            }
            #pragma unroll
            for (int i = 0; i < 8; ++i) {             // B: 128 k x 64 n -> B^T
                int slot = i * 256 + t;
                int bk = slot >> 4, bn4 = (slot & 15) << 2;
                float4 v = *(const float4*)(W + (kc + bk) * 256 + n0 + bn4);
                Bbf[(bn4 + 0) * 136 + bk] = f2bf(v.x);
                Bbf[(bn4 + 1) * 136 + bk] = f2bf(v.y);
                Bbf[(bn4 + 2) * 136 + bk] = f2bf(v.z);
                Bbf[(bn4 + 3) * 136 + bk] = f2bf(v.w);
            }
            __syncthreads();
            #pragma unroll
            for (int s = 0; s < 4; ++s) {
                const int kb = s * 32 + quad * 8;
                bf16x8 a = *(const bf16x8*)(Abf + (w * 16 + lr) * 136 + kb);
                #pragma unroll
                for (int nc = 0; nc < 4; ++nc) {
                    bf16x8 b = *(const bf16x8*)(Bbf + (nc * 16 + lr) * 136 + kb);
                    acc[nc] = __builtin_amdgcn_mfma_f32_16x16x32_bf16(a, b, acc[nc], 0, 0, 0);
                }
            }
            __syncthreads();
        }

        #pragma unroll
        for (int nc = 0; nc < 4; ++nc) {
            const int col = n0 + nc * 16 + lr;
            const float bv = bias ? bias[col] : 0.f;
            #pragma unroll
            for (int reg = 0; reg < 4; ++reg) {
                int row  = r0 + w * 16 + quad * 4 + reg;   // = l*2+b
                int orow = ((row & 1) << 9) + (row >> 1);
                outp[orow * 256 + col] = acc[nc][reg] + bv;
            }
        }
    } else {
        // ---------------- affinity path (identical math to R16/R17)
        const int aidx = (bid / 3) * 2 + r3;  // [0,512)
        const int l0 = (aidx & 15) * 32;
        const int m0 = ((aidx >> 4) & 15) * 32;
        const int b  = aidx >> 8;

        float* E1s  = (float*)smem;           // [32][132]
        float* E2s  = E1s + 32 * 132;         // [32][132]
        float* affs = E2s + 32 * 132;         // [32][36]

        const int tl = t >> 4, tm = t & 15;   // cells: l in {tl,tl+16}, m in {tm,tm+16}
        float acc[2][2] = {};

        for (int kc = 0; kc < 256; kc += 128) {
            #pragma unroll
            for (int i = 0; i < 4; ++i) {             // 32 rows x 128 k, both panels
                int slot = i * 256 + t;
                int r = slot >> 5, kq = (slot & 31) << 2;
                *(float4*)(E1s + r * 132 + kq) =
                    *(const float4*)(E1g + (((b << 9) + l0 + r) << 8) + kc + kq);
                *(float4*)(E2s + r * 132 + kq) =
                    *(const float4*)(E2g + (((b << 9) + m0 + r) << 8) + kc + kq);
            }
            __syncthreads();
            #pragma unroll 4
            for (int k0 = 0; k0 < 128; k0 += 4) {
                const float4 w  = *(const float4*)(wo + kc + k0);   // uniform -> s_load
                const float4 a0 = *(const float4*)(E1s + tl * 132 + k0);
                const float4 a1 = *(const float4*)(E1s + (tl + 16) * 132 + k0);
                const float4 q0 = *(const float4*)(E2s + tm * 132 + k0);
                const float4 q1 = *(const float4*)(E2s + (tm + 16) * 132 + k0);
                PAIR(a0, q0, w, acc[0][0]);
                PAIR(a0, q1, w, acc[0][1]);
                PAIR(a1, q0, w, acc[1][0]);
                PAIR(a1, q1, w, acc[1][1]);
            }
            __syncthreads();
        }

        // aff = -2*acc (the -2*wo factor folded); E = exp(aff), SW cancels
        affs[tl * 36 + tm]             = __builtin_amdgcn_exp2f(acc[0][0] * N2LOG2E);
        affs[tl * 36 + tm + 16]        = __builtin_amdgcn_exp2f(acc[0][1] * N2LOG2E);
        affs[(tl + 16) * 36 + tm]      = __builtin_amdgcn_exp2f(acc[1][0] * N2LOG2E);
        affs[(tl + 16) * 36 + tm + 16] = __builtin_amdgcn_exp2f(acc[1][1] * N2LOG2E);
        __syncthreads();

        const int r  = t >> 3;
        const int c4 = (t & 7) << 2;
        // natural: EN[l][m]=bf16(E*p1[l]); S1[l]+=sum_m E*p2[m]
        {
            float4 e = *(const float4*)(affs + r * 36 + c4);
            const float p1r = p1g[(b << 9) + l0 + r];
            short4 vn;
            vn.x = f2bf(e.x * p1r); vn.y = f2bf(e.y * p1r);
            vn.z = f2bf(e.z * p1r); vn.w = f2bf(e.w * p1r);
            *(short4*)(EN + (((b << 9) + l0 + r) << 9) + m0 + c4) = vn;
            float4 p2v = *(const float4*)(p2g + (b << 9) + m0 + c4);
            float s = (e.x * p2v.x + e.y * p2v.y) + (e.z * p2v.z + e.w * p2v.w);
            s += __shfl_xor(s, 1, 64);
            s += __shfl_xor(s, 2, 64);
            s += __shfl_xor(s, 4, 64);
            if ((t & 7) == 0) atomicAdd(S1 + (b << 9) + l0 + r, s);
        }
        // transposed: ET[m][l]=bf16(E^T*p2[m]); S2[m]+=sum_l E*p1[l]
        {
            float4 te;
            te.x = affs[(c4 + 0) * 36 + r];
            te.y = affs[(c4 + 1) * 36 + r];
            te.z = affs[(c4 + 2) * 36 + r];
            te.w = affs[(c4 + 3) * 36 + r];
            const float p2r = p2g[(b << 9) + m0 + r];
            short4 vt;
            vt.x = f2bf(te.x * p2r); vt.y = f2bf(te.y * p2r);
            vt.z = f2bf(te.z * p2r); vt.w = f2bf(te.w * p2r);
            *(short4*)(ET + (((b << 9) + m0 + r) << 9) + l0 + c4) = vt;
            float4 p1v = *(const float4*)(p1g + (b << 9) + l0 + c4);
            float s = (te.x * p1v.x + te.y * p1v.y) + (te.z * p1v.z + te.w * p1v.w);
            s += __shfl_xor(s, 1, 64);
            s += __shfl_xor(s, 2, 64);
            s += __shfl_xor(s, 4, 64);
            if ((t & 7) == 0) atomicAdd(S2 + (b << 9) + m0 + r, s);
        }
    }
}

// --------------------------------------------------------------- k_final
// Double-buffered LDS: stage chunk c+1 overlaps MFMA on chunk c.
__global__ __launch_bounds__(256) void k_final(
    const short* __restrict__ EN, const short* __restrict__ ET,
    const float* __restrict__ U1, const float* __restrict__ U2,
    const float* __restrict__ P12, const float* __restrict__ P21,
    const float* __restrict__ S1, const float* __restrict__ S2,
    float* __restrict__ out)
{
    const int t   = threadIdx.x;
    const int r0  = blockIdx.x * 32, n0 = blockIdx.y * 32;
    const int dir = blockIdx.z >> 1, b = blockIdx.z & 1;
    const short* Ag = (dir == 0 ? ET  : EN)  + b * 262144;  // [row][k] bf16, stride 512
    const float* Sg = (dir == 0 ? S1  : S2)  + b * 512;
    const float* Bg = (dir == 0 ? U1  : U2)  + b * 131072;  // [k][n], stride 256
    const float* Pg = (dir == 0 ? P12 : P21) + b * 131072;  // [row][n], stride 256
    float* o = out + (dir == 0 ? 262144 : 0);

    __shared__ __align__(16) short Abf0[32 * 136];  // ping
    __shared__ __align__(16) short Bbf0[32 * 136];
    __shared__ __align__(16) short Abf1[32 * 136];  // pong
    __shared__ __align__(16) short Bbf1[32 * 136];
    __shared__ __align__(16) float rs[512];

    for (int i = t; i < 512; i += 256)
        rs[i] = __builtin_amdgcn_rcpf(Sg[i]);

    const int w    = t >> 6;
    const int lane = t & 63;
    const int quad = lane >> 4;
    const int lr   = lane & 15;
    const int wr   = (w >> 1) << 4, wc = (w & 1) << 4;
    const int col  = n0 + wc + lr;

    float pre[4];                          // Pg epilogue prefetch
    #pragma unroll
    for (int reg = 0; reg < 4; ++reg) {
        const int m = r0 + wr + quad * 4 + reg;
        pre[reg] = Pg[(m << 8) + col];
    }
    __syncthreads();                       // rs visible

    f32x4 acc = {};

#define STAGE(Ab, Bb, kc) do {                                            \
    _Pragma("unroll")                                                     \
    for (int i = 0; i < 2; ++i) {              /* A: raw bf16 copy */     \
        int slot = i * 256 + t;                                           \
        int r = slot >> 4, k8 = (slot & 15) << 3;                         \
        *(bf16x8*)((Ab) + r * 136 + k8) =                                 \
            *(const bf16x8*)(Ag + ((r0 + r) << 9) + (kc) + k8);           \
    }                                                                     \
    _Pragma("unroll")                                                     \
    for (int i = 0; i < 4; ++i) {              /* B: rs folded */         \
        int slot = i * 256 + t;                                           \
        int bk = slot >> 3, bn4 = (slot & 7) << 2;                        \
        float4 v = *(const float4*)(Bg + (((kc) + bk) << 8) + n0 + bn4);  \
        const float rsv = rs[(kc) + bk];                                  \
        (Bb)[(bn4 + 0) * 136 + bk] = f2bf(v.x * rsv);                     \
        (Bb)[(bn4 + 1) * 136 + bk] = f2bf(v.y * rsv);                     \
        (Bb)[(bn4 + 2) * 136 + bk] = f2bf(v.z * rsv);                     \
        (Bb)[(bn4 + 3) * 136 + bk] = f2bf(v.w * rsv);                     \
    }                                                                     \
} while (0)

#define COMPUTE(Ab, Bb) do {                                              \
    _Pragma("unroll")                                                     \
    for (int s = 0; s < 4; ++s) {                                         \
        const int kb = s * 32 + quad * 8;                                 \
        bf16x8 a_  = *(const bf16x8*)((Ab) + (wr + lr) * 136 + kb);       \
        bf16x8 bb_ = *(const bf16x8*)((Bb) + (wc + lr) * 136 + kb);       \
        acc = __builtin_amdgcn_mfma_f32_16x16x32_bf16(a_, bb_, acc, 0, 0, 0); \
    }                                                                     \
} while (0)

    STAGE(Abf0, Bbf0, 0);
    __syncthreads();                       // buf0 ready
    STAGE(Abf1, Bbf1, 128);                // overlap with compute(0)
    COMPUTE(Abf0, Bbf0);
    __syncthreads();                       // buf1 ready, buf0 reads done
    STAGE(Abf0, Bbf0, 256);
    COMPUTE(Abf1, Bbf1);
    __syncthreads();
    STAGE(Abf1, Bbf1, 384);
    COMPUTE(Abf0, Bbf0);
    __syncthreads();
    COMPUTE(Abf1, Bbf1);

#undef STAGE
#undef COMPUTE

    #pragma unroll
    for (int reg = 0; reg < 4; ++reg) {
        const int m = r0 + wr + quad * 4 + reg;
        float v = acc[reg] + pre[reg];
        float tv = 1.f - 2.f * __builtin_amdgcn_rcpf(
                       __builtin_amdgcn_exp2f(v * TWO_LOG2E) + 1.f);
        o[((m << 1) + b) * 256 + col] = tv;
    }
}

// ---------------------------------------------------------------- launch
extern "C" void kernel_launch(void* const* d_in, const int* in_sizes, int n_in,
                              void* d_out, int out_size, void* d_ws, size_t ws_size,
                              hipStream_t stream)
{
    const float* ctx1 = (const float*)d_in[0];
    const float* ctx2 = (const float*)d_in[1];
    const float* m1   = (const float*)d_in[2];
    const float* m2   = (const float*)d_in[3];
    const float* Wh   = (const float*)d_in[4];
    const float* bh   = (const float*)d_in[5];
    const float* wo   = (const float*)d_in[6];
    const float* W12  = (const float*)d_in[7];
    const float* b12  = (const float*)d_in[8];
    const float* W21  = (const float*)d_in[9];
    const float* b21  = (const float*)d_in[10];
    float* out = (float*)d_out;
    float* ws  = (float*)d_ws;

    float* E1  = ws;                 // 262144
    float* E2  = E1  + 262144;
    float* P12 = E2  + 262144;
    float* U1  = P12 + 262144;
    float* P21 = U1  + 262144;
    float* U2  = P21 + 262144;
    float* p1  = U2  + 262144;       // 1024
    float* p2  = p1  + 1024;
    float* S1  = p2  + 1024;         // 1024
    float* S2  = S1  + 1024;
    float* ENf = S2  + 1024;         // 524288 floats reserved
    float* ETf = ENf + 524288;       // 524288 floats reserved
    short* EN16 = (short*)ENf;       // [2][512][512] bf16
    short* ET16 = (short*)ETf;       // [2][512][512] bf16

    hipLaunchKernelGGL(k_projE, dim3(32, 4, 2), dim3(256), 0, stream,
                       ctx1, ctx2, Wh, bh, m1, m2, E1, E2, p1, p2, S1, S2);
    hipLaunchKernelGGL(k_mid, dim3(768, 1, 1), dim3(256), 0, stream,
                       ctx1, ctx2, W12, b12, W21, b21,
                       E1, E2, wo, p1, p2,
                       P12, U1, P21, U2, EN16, ET16, S1, S2);
    hipLaunchKernelGGL(k_final, dim3(16, 8, 4), dim3(256), 0, stream,
                       EN16, ET16, U1, U2, P12, P21, S1, S2, out);
}